// Round 3
// baseline (4530.190 us; speedup 1.0000x reference)
//
#include <hip/hip_runtime.h>

// Problem constants
#define B_   16
#define C_   64
#define H_   64
#define W_   64
#define HD_  128
#define K_   320      // C + 2*HD
#define SW_  127      // H+W-1

// Decomposition: 4 hd-groups (32 hd each) x 64 col-clusters (16 cols each) = 256 blocks
#define NG    4
#define GH    32      // hd per group
#define NCG   64      // clusters
#define TC    16      // cols per cluster
#define NT    640     // threads per block (10 waves)
#define ROWS  160     // gate rows per block (5 gates x 32 hd)
#define SSTR  17      // LDS stride (bank-spread)

// Workspace layout (floats)
#define HB0  0
#define HB1  131072
#define CB0  262144
#define CB1  393216
#define WB   524288                  // Wb: 4 * 320 * 160 = 204800 floats
#define CNT  729088                  // 64 counters, stride 32 ints (128 B)
#define GCNT (729088 + 2048)
#define WS_TOT (729088 + 4096)

__device__ __forceinline__ float sigm(float v) { return 1.f / (1.f + __expf(-v)); }
__device__ __forceinline__ float tanh_fast(float v) {
    float e = __expf(2.f * v);
    return 1.f - 2.f / (e + 1.f);
}

// Coherence-point (agent-scope) scalar access: bypasses per-XCD L1/L2 staleness.
__device__ __forceinline__ float gload(const float* p) {
    return __hip_atomic_load((float*)p, __ATOMIC_RELAXED, __HIP_MEMORY_SCOPE_AGENT);
}
__device__ __forceinline__ void gstore(float* p, float v) {
    __hip_atomic_store(p, v, __ATOMIC_RELAXED, __HIP_MEMORY_SCOPE_AGENT);
}
__device__ __forceinline__ void wait_ge(int* p, int tgt) {
    while (__hip_atomic_load(p, __ATOMIC_RELAXED, __HIP_MEMORY_SCOPE_AGENT) < tgt)
        __builtin_amdgcn_s_sleep(1);
    __atomic_signal_fence(__ATOMIC_ACQUIRE);
}
__device__ __forceinline__ void bump(int* p) {
    __hip_atomic_fetch_add(p, 1, __ATOMIC_RELEASE, __HIP_MEMORY_SCOPE_AGENT);
}

// ---------------------------------------------------------------------------
// Prep: zero state ping-pong + counters; build Wb[g][k][160] (k-major weights).
// k in [0,64): w_is;  k in [64,192): w_ss[...,1] (h_prev);  k in [192,320): w_ss[...,0] (h_sh)
// local row lr = q*32 + hl  ->  global o = q*128 + g*32 + hl
// ---------------------------------------------------------------------------
__global__ void lstm_prep(const float* __restrict__ w_is,
                          const float* __restrict__ w_ss,
                          float* __restrict__ ws, long long n_ws)
{
    long long total = (long long)WS_TOT;
    if (total > n_ws) total = n_ws;
    const long long stride = (long long)gridDim.x * blockDim.x;
    for (long long idx = (long long)blockIdx.x * blockDim.x + threadIdx.x; idx < total; idx += stride) {
        if (idx < (long long)WB || idx >= (long long)CNT) {
            ws[idx] = 0.f;                       // state ping-pong / counters
        } else {
            int r  = (int)(idx - WB);            // [0, 204800)
            int g  = r / (K_ * ROWS);
            int rm = r % (K_ * ROWS);
            int k  = rm / ROWS;
            int lr = rm % ROWS;
            int q  = lr >> 5, hl = lr & 31;
            int o  = q * HD_ + g * GH + hl;
            float v;
            if (k < C_)            v = w_is[o * C_ + k];
            else if (k < C_ + HD_) v = w_ss[(o * HD_ + (k - C_)) * 2 + 1];
            else                   v = w_ss[(o * HD_ + (k - C_ - HD_)) * 2 + 0];
            ws[idx] = v;
        }
    }
}

// ---------------------------------------------------------------------------
// Persistent kernel: 127 diagonal steps, cluster-local dataflow sync.
// Block (g, cgp): gate rows {q*128 + g*32 + hl}, cols n in [cgp*16, cgp*16+16).
// State layout: buf[n*128 + hd], accessed only via agent-scope atomics.
// cnt[c]  = arrivals at end-of-step   (hits 4*(j+1) when cluster c finished step j)
// gcnt[c] = arrivals at end-of-gather (hits 4*(j+1) when cluster c read step-j inputs)
// ---------------------------------------------------------------------------
__global__ void __launch_bounds__(NT) lstm_persist(
    const float* __restrict__ x,
    const float* __restrict__ Wb,
    const float* __restrict__ b_is,
    const float* __restrict__ b_ss,
    float* __restrict__ out,
    float* __restrict__ ws)
{
    __shared__ float Ss[K_ * SSTR];   // S-panel [k][col]; reused as gate panel [160][col]
    __shared__ float Cs[17 * GH];     // c panel [colp][hl], colp=0 is left-boundary col
    __shared__ float bias_s[ROWS];

    const int tid = threadIdx.x;
    const int cgp = blockIdx.x >> 2;
    const int g   = blockIdx.x & 3;
    const int n0  = cgp * TC;
    const int inb  = (n0 & 63) != 0;          // has left neighbor within same b
    const int hasr = ((n0 + TC) & 63) != 0;   // has right neighbor within same b

    int* cntp  = (int*)(ws + CNT);
    int* gcntp = (int*)(ws + GCNT);

    if (tid < ROWS) {
        int q = tid >> 5, hl = tid & 31;
        int o = q * HD_ + g * GH + hl;
        bias_s[tid] = b_is[o] + b_ss[o];
    }

    const float* __restrict__ Wg = Wb + (size_t)g * (K_ * ROWS);
    const int rt = tid >> 4;   // 0..39 -> rows 4rt..4rt+3
    const int ct = tid & 15;   // column

    for (int j = 0; j < SW_; ++j) {
        const float* hc = ws + ((j & 1) ? HB1 : HB0);
        const float* cc = ws + ((j & 1) ? CB1 : CB0);
        float*       hn = ws + ((j & 1) ? HB0 : HB1);
        float*       cn = ws + ((j & 1) ? CB0 : CB1);

        // ---- wait for RAW deps: own cluster + left neighbor finished step j-1 ----
        if (j > 0 && tid == 0) {
            wait_ge(cntp + cgp * 32, 4 * j);
            if (inb) wait_ge(cntp + (cgp - 1) * 32, 4 * j);
        }
        __syncthreads();

        // ---- gather S panel ----
        // x part: k = c in [0,64)  (read-only input: normal cached loads)
        for (int idx = tid; idx < C_ * TC; idx += NT) {
            int c = idx & 63, col = idx >> 6;
            int n = n0 + col, b = n >> 6, hr = n & 63;
            int w = j - hr;
            float v = 0.f;
            if ((unsigned)w < (unsigned)W_)
                v = x[(((size_t)b * C_ + c) * H_ + hr) * W_ + w];
            Ss[c * SSTR + col] = v;
        }
        // h parts (agent-scope loads): part0 k=64+i (h_prev), part1 k=192+i (h shifted)
        for (int idx = tid; idx < 2 * HD_ * TC; idx += NT) {
            int i    = idx & 127;
            int col  = (idx >> 7) & (TC - 1);
            int part = idx >> 11;
            int n = n0 + col, hr = n & 63;
            float v; int k;
            if (part == 0) { v = gload(hc + (size_t)n * HD_ + i);                  k = C_ + i; }
            else           { v = hr ? gload(hc + (size_t)(n - 1) * HD_ + i) : 0.f; k = C_ + HD_ + i; }
            Ss[k * SSTR + col] = v;
        }
        // c panel (agent-scope loads): Cs[colp][hl], colp in [0,17), col = n0-1+colp
        if (tid < 17 * GH) {
            int colp = tid >> 5, hl = tid & 31;
            int n = n0 - 1 + colp;
            float v = 0.f;
            if (colp > 0 || inb)
                v = gload(cc + (size_t)n * HD_ + g * GH + hl);
            Cs[colp * GH + hl] = v;
        }
        __syncthreads();
        if (tid == 0) bump(gcntp + cgp * 32);   // all step-j inputs read

        // ---- GEMM: 160 rows x 16 cols, K=320; W streams from L2, S from LDS ----
        float4 acc = make_float4(0.f, 0.f, 0.f, 0.f);
        {
            const float* wp = Wg + 4 * rt;
            const float* sp = Ss + ct;
            #pragma unroll 8
            for (int k = 0; k < K_; ++k) {
                float4 wv = *(const float4*)(wp + (size_t)k * ROWS);
                float  sv = sp[k * SSTR];
                acc.x += wv.x * sv;
                acc.y += wv.y * sv;
                acc.z += wv.z * sv;
                acc.w += wv.w * sv;
            }
        }
        __syncthreads();   // S reads done; safe to overwrite Ss with gates

        Ss[(4 * rt + 0) * SSTR + ct] = acc.x;
        Ss[(4 * rt + 1) * SSTR + ct] = acc.y;
        Ss[(4 * rt + 2) * SSTR + ct] = acc.z;
        Ss[(4 * rt + 3) * SSTR + ct] = acc.w;

        // ---- WAR guard: right neighbor must have gathered step j-1 inputs
        //      before we overwrite ping-pong buffer parity (j+1)&1 ----
        if (j > 0 && hasr && tid == 0) wait_ge(gcntp + (cgp + 1) * 32, 4 * j);
        __syncthreads();

        // ---- nonlinearity + state update + streaming output ----
        if (tid < GH * TC) {
            int hl = tid & 31, col = tid >> 5;
            int n = n0 + col, b = n >> 6, hr = n & 63;
            int hd = g * GH + hl;
            float go  = Ss[(0 * GH + hl) * SSTR + col] + bias_s[0 * GH + hl];
            float gfl = Ss[(1 * GH + hl) * SSTR + col] + bias_s[1 * GH + hl];
            float gfu = Ss[(2 * GH + hl) * SSTR + col] + bias_s[2 * GH + hl];
            float gi  = Ss[(3 * GH + hl) * SSTR + col] + bias_s[3 * GH + hl];
            float gg  = Ss[(4 * GH + hl) * SSTR + col] + bias_s[4 * GH + hl];
            float so = sigm(go), sfl = sigm(gfl), sfu = sigm(gfu), si = sigm(gi);
            float tg = tanh_fast(gg);
            float cp = Cs[(col + 1) * GH + hl];
            float cs = hr ? Cs[col * GH + hl] : 0.f;
            float cv = sfl * cp + sfu * cs + si * tg;
            float hv = so * tanh_fast(cv);
            size_t sidx = (size_t)n * HD_ + hd;
            gstore(cn + sidx, cv);
            gstore(hn + sidx, hv);
            int w = j - hr;
            if ((unsigned)w < (unsigned)W_)
                out[(((size_t)b * HD_ + hd) * H_ + hr) * W_ + w] = hv;
        }
        __syncthreads();
        if (tid == 0) bump(cntp + cgp * 32);    // step j finished
    }
}

// ---------------------------------------------------------------------------
extern "C" void kernel_launch(void* const* d_in, const int* in_sizes, int n_in,
                              void* d_out, int out_size, void* d_ws, size_t ws_size,
                              hipStream_t stream)
{
    const float* x    = (const float*)d_in[0];
    const float* w_is = (const float*)d_in[1];
    const float* b_is = (const float*)d_in[2];
    const float* w_ss = (const float*)d_in[3];
    const float* b_ss = (const float*)d_in[4];
    float* out = (float*)d_out;
    float* ws  = (float*)d_ws;

    const long long n_ws = (long long)(ws_size / 4);

    hipLaunchKernelGGL(lstm_prep, dim3(512), dim3(256), 0, stream, w_is, w_ss, ws, n_ws);

    const float* Wbp = ws + WB;
    hipLaunchKernelGGL(lstm_persist, dim3(NG * NCG), dim3(NT), 0, stream,
                       x, Wbp, b_is, b_ss, out, ws);
}

// Round 5
// 2046.628 us; speedup vs baseline: 2.2135x; 2.2135x over previous
//
#include <hip/hip_runtime.h>

typedef __attribute__((ext_vector_type(8))) short bf16x8;
typedef __attribute__((ext_vector_type(4))) float f32x4;

// Problem constants
#define B_   16
#define C_   64
#define H_   64
#define W_   64
#define HD_  128
#define K_   320      // C + 2*HD
#define SW_  127      // H+W-1

// Decomposition: 4 hd-groups (32 hd each) x 64 col-clusters (16 cols each) = 256 blocks
#define NG    4
#define GH    32      // hd per group
#define NCG   64      // clusters
#define TC    16      // cols per cluster
#define NT    640     // threads per block (10 waves)
#define ROWS  160     // gate rows per block (5 gates x 32 hd)
#define NKT   10      // K/32 k-tiles
#define NRT   10      // ROWS/16 row-tiles (== waves)
#define SS18  18      // Ss row stride (17 cols + pad)

// Workspace layout (float offsets)
#define HB0  0
#define HB1  131072
#define CB0  262144
#define CB1  393216
#define CNT  524288                 // 64 counters, stride 32 ints
#define GCNT (524288 + 2048)
#define AFB  528384                 // A-fragments: 204800 floats (hi+lo bf16 pairs)
#define XT   (528384 + 204800)      // xT: B*H*W*C = 4194304 floats
#define XT_N 4194304LL              // (R4 bug: was 16777216 -> OOB reads of x -> abort)
#define WS_MIN   ((long long)XT)
#define WS_XT    ((long long)XT + XT_N)

__device__ __forceinline__ float sigm(float v) { return 1.f / (1.f + __expf(-v)); }
__device__ __forceinline__ float tanh_fast(float v) {
    float e = __expf(2.f * v);
    return 1.f - 2.f / (e + 1.f);
}

// Coherence-point (agent-scope) access: immune to per-XCD L2 staleness.
__device__ __forceinline__ float gload(const float* p) {
    return __hip_atomic_load((float*)p, __ATOMIC_RELAXED, __HIP_MEMORY_SCOPE_AGENT);
}
__device__ __forceinline__ void gstore(float* p, float v) {
    __hip_atomic_store(p, v, __ATOMIC_RELAXED, __HIP_MEMORY_SCOPE_AGENT);
}
__device__ __forceinline__ void wait_ge(int* p, int tgt) {
    while (__hip_atomic_load(p, __ATOMIC_RELAXED, __HIP_MEMORY_SCOPE_AGENT) < tgt)
        __builtin_amdgcn_s_sleep(1);
    __atomic_signal_fence(__ATOMIC_ACQUIRE);
}
__device__ __forceinline__ void bump(int* p) {
    __hip_atomic_fetch_add(p, 1, __ATOMIC_RELEASE, __HIP_MEMORY_SCOPE_AGENT);
}

__device__ __forceinline__ uint bf16hi(uint u) { return (u + 0x7FFFu + ((u >> 16) & 1u)) >> 16; }

// ---------------------------------------------------------------------------
// Prep: zero state+flags; build A-fragments (split-bf16, MFMA lane order);
// build xT[b][hr][w][c] for coalesced per-step x gather.
// A-frag chunk (g, rt, kt): 64 lanes x (8 hi + 8 lo) bf16 = 2048 B.
//   element: m=lane&15, quad=lane>>4, jj in [0,8): A[rt*16+m][kt*32+quad*8+jj]
//   row r = q*32+hl -> global o = q*128 + g*32 + hl
//   k<64: w_is; 64<=k<192: w_ss[...,1] (h_prev); k>=192: w_ss[...,0] (h_sh)
// ---------------------------------------------------------------------------
__global__ void lstm_prep(const float* __restrict__ x,
                          const float* __restrict__ w_is,
                          const float* __restrict__ w_ss,
                          float* __restrict__ ws, int use_xt, long long n_ws)
{
    const long long stride = (long long)gridDim.x * blockDim.x;
    const long long t0 = (long long)blockIdx.x * blockDim.x + threadIdx.x;

    // 1) zero state ping-pong + flags
    long long zt = (long long)AFB; if (zt > n_ws) zt = n_ws;
    for (long long i = t0; i < zt; i += stride) ws[i] = 0.f;

    // 2) A-fragments
    if (n_ws >= WS_MIN) {
        ushort* af = (ushort*)(ws + AFB);
        for (long long e = t0; e < 204800; e += stride) {
            int idx   = (int)e;
            int chunk = idx >> 9;           // (g*NRT+rt)*NKT + kt
            int lane  = (idx >> 3) & 63;
            int jj    = idx & 7;
            int g  = chunk / (NRT * NKT);
            int rm = chunk % (NRT * NKT);
            int rt = rm / NKT, kt = rm % NKT;
            int m = lane & 15, quad = lane >> 4;
            int r = rt * 16 + m;
            int q = r >> 5, hl = r & 31;
            int o = q * HD_ + g * GH + hl;
            int k = kt * 32 + quad * 8 + jj;
            float v;
            if (k < C_)            v = w_is[o * C_ + k];
            else if (k < C_ + HD_) v = w_ss[(o * HD_ + (k - C_)) * 2 + 1];
            else                   v = w_ss[(o * HD_ + (k - C_ - HD_)) * 2 + 0];
            uint uh = bf16hi(__float_as_uint(v));
            float rl = v - __uint_as_float(uh << 16);
            uint ul = bf16hi(__float_as_uint(rl));
            int base = chunk * 1024 + lane * 16 + jj;   // ushort units
            af[base]     = (ushort)uh;
            af[base + 8] = (ushort)ul;
        }
    }

    // 3) xT transpose: exactly B*H*W*C elements, b in [0,16)
    if (use_xt) {
        float* xt = ws + XT;
        for (long long e = t0; e < XT_N; e += stride) {
            int c  = (int)(e & 63);
            int w  = (int)((e >> 6) & 63);
            int hr = (int)((e >> 12) & 63);
            int b  = (int)(e >> 18);        // < 16 now that XT_N = 2^22
            xt[e] = x[(((size_t)b * C_ + c) * H_ + hr) * W_ + w];
        }
    }
}

// ---------------------------------------------------------------------------
// Persistent kernel: 127 diagonal steps, cluster-local dataflow sync (as R3),
// GEMM via split-bf16 MFMA 16x16x32.
// Block (g, cgp): gate rows {q*128 + g*32 + hl}, cols n in [cgp*16, cgp*16+16).
// ---------------------------------------------------------------------------
__global__ void __launch_bounds__(NT) lstm_persist(
    const float* __restrict__ x,
    const float* __restrict__ ws_c,
    const float* __restrict__ b_is,
    const float* __restrict__ b_ss,
    float* __restrict__ out,
    float* __restrict__ ws,
    int use_xt)
{
    __shared__ float Ss[192 * SS18];    // rows 0..63: x [k][col+1]; 64..191: h [i][col'] (17 wide); reused as gate panel [160][17]
    __shared__ uint  Bf[NKT * 576];     // S-fragments: per kt, 64 lanes x (16B hi + 16B lo), swizzled
    __shared__ float Cs[17 * GH];       // c panel [colp][hl]
    __shared__ float bias_s[ROWS];

    const int tid = threadIdx.x;
    const int cgp = blockIdx.x >> 2;
    const int g   = blockIdx.x & 3;
    const int n0  = cgp * TC;
    const int inb  = (n0 & 63) != 0;
    const int hasr = ((n0 + TC) & 63) != 0;

    int* cntp  = (int*)(ws + CNT);
    int* gcntp = (int*)(ws + GCNT);
    const float* xt = ws_c + XT;
    const uint4* afq = (const uint4*)(ws_c + AFB);

    if (tid < ROWS) {
        int q = tid >> 5, hl = tid & 31;
        int o = q * HD_ + g * GH + hl;
        bias_s[tid] = b_is[o] + b_ss[o];
    }

    const int lane = tid & 63;
    const int wv   = tid >> 6;          // wave = row-tile rt in [0,10)
    const int quad = lane >> 4;
    const int colc = lane & 15;
    const uint4* ap0 = afq + (size_t)((g * NRT + wv) * NKT) * 128 + lane * 2;
    uint* bfp = &Bf[lane * 8 + ((lane >> 2) << 2)];

    for (int j = 0; j < SW_; ++j) {
        const float* hc = ws + ((j & 1) ? HB1 : HB0);
        const float* cc = ws + ((j & 1) ? CB1 : CB0);
        float*       hn = ws + ((j & 1) ? HB0 : HB1);
        float*       cn = ws + ((j & 1) ? CB0 : CB1);

        // ---- RAW wait: own cluster + left neighbor finished step j-1 ----
        if (j > 0 && tid == 0) {
            wait_ge(cntp + cgp * 32, 4 * j);
            if (inb) wait_ge(cntp + (cgp - 1) * 32, 4 * j);
        }
        __syncthreads();

        // ---- gather: x (coalesced via xT), h (17 cols incl left boundary), c panel ----
        for (int idx = tid; idx < C_ * TC; idx += NT) {
            int c = idx & 63, col = idx >> 6;
            int n = n0 + col, b = n >> 6, hr = n & 63;
            int w = j - hr;
            float v = 0.f;
            if ((unsigned)w < (unsigned)W_)
                v = use_xt ? xt[(((size_t)b * H_ + hr) * W_ + w) * C_ + c]
                           : x [(((size_t)b * C_ + c) * H_ + hr) * W_ + w];
            Ss[c * SS18 + col + 1] = v;
        }
        for (int idx = tid; idx < HD_ * 17; idx += NT) {
            int i = idx & 127, colp = idx >> 7;          // colp in [0,17)
            int n = n0 - 1 + colp;
            float v = (colp > 0 || inb) ? gload(hc + (size_t)n * HD_ + i) : 0.f;
            Ss[(64 + i) * SS18 + colp] = v;
        }
        if (tid < 17 * GH) {
            int colp = tid >> 5, hl = tid & 31;
            int n = n0 - 1 + colp;
            float v = (colp > 0 || inb) ? gload(cc + (size_t)n * HD_ + g * GH + hl) : 0.f;
            Cs[colp * GH + hl] = v;
        }
        __syncthreads();
        if (tid == 0) bump(gcntp + cgp * 32);   // all step-(j-1)-state reads done

        // ---- convert S panel to split-bf16 B-fragments ----
        // thread -> (kt = wv, lane): B[n=lane&15][k=kt*32+quad*8+jj]
        {
            int kb = wv * 32 + quad * 8;   // wv == kt here (10 waves == 10 k-tiles)
            uint hv[4], lv[4];
            #pragma unroll
            for (int p = 0; p < 4; ++p) {
                int k0 = kb + 2 * p;
                // k<192: own col (col+1 slot); k>=192: shifted -> left slot (col)
                float v0 = (k0 < 192) ? Ss[k0 * SS18 + colc + 1] : Ss[(k0 - 128) * SS18 + colc];
                int k1 = k0 + 1;
                float v1 = (k1 < 192) ? Ss[k1 * SS18 + colc + 1] : Ss[(k1 - 128) * SS18 + colc];
                uint h0 = bf16hi(__float_as_uint(v0));
                uint h1 = bf16hi(__float_as_uint(v1));
                float r0 = v0 - __uint_as_float(h0 << 16);
                float r1 = v1 - __uint_as_float(h1 << 16);
                uint l0 = bf16hi(__float_as_uint(r0));
                uint l1 = bf16hi(__float_as_uint(r1));
                hv[p] = h0 | (h1 << 16);
                lv[p] = l0 | (l1 << 16);
            }
            uint* bp = bfp + wv * 576;
            *(uint4*)bp       = make_uint4(hv[0], hv[1], hv[2], hv[3]);
            *(uint4*)(bp + 4) = make_uint4(lv[0], lv[1], lv[2], lv[3]);
        }
        __syncthreads();

        // ---- GEMM: wave wv computes rows [wv*16, wv*16+16) x 16 cols, K=320 ----
        f32x4 acc = {0.f, 0.f, 0.f, 0.f};
        #pragma unroll
        for (int kt = 0; kt < NKT; ++kt) {
            uint4 ha = ap0[kt * 128];
            uint4 la = ap0[kt * 128 + 1];
            const uint* bp = bfp + kt * 576;
            uint4 hb = *(const uint4*)bp;
            uint4 lb = *(const uint4*)(bp + 4);
            bf16x8 Ah = *(bf16x8*)&ha, Al = *(bf16x8*)&la;
            bf16x8 Bh = *(bf16x8*)&hb, Bl = *(bf16x8*)&lb;
            acc = __builtin_amdgcn_mfma_f32_16x16x32_bf16(Ah, Bh, acc, 0, 0, 0);
            acc = __builtin_amdgcn_mfma_f32_16x16x32_bf16(Ah, Bl, acc, 0, 0, 0);
            acc = __builtin_amdgcn_mfma_f32_16x16x32_bf16(Al, Bh, acc, 0, 0, 0);
        }

        // ---- write gates to LDS panel (C/D layout: row = quad*4+reg, col = lane&15) ----
        #pragma unroll
        for (int r = 0; r < 4; ++r)
            Ss[(wv * 16 + quad * 4 + r) * 17 + colc] = acc[r];

        // ---- WAR guard: right neighbor gathered step j-1 before we overwrite parity ----
        if (j > 0 && hasr && tid == 0) wait_ge(gcntp + (cgp + 1) * 32, 4 * j);
        __syncthreads();

        // ---- nonlinearity + state update + streaming output ----
        if (tid < GH * TC) {
            int hl = tid & 31, col = tid >> 5;
            int n = n0 + col, b = n >> 6, hr = n & 63;
            int hd = g * GH + hl;
            float go  = Ss[(0 * GH + hl) * 17 + col] + bias_s[0 * GH + hl];
            float gfl = Ss[(1 * GH + hl) * 17 + col] + bias_s[1 * GH + hl];
            float gfu = Ss[(2 * GH + hl) * 17 + col] + bias_s[2 * GH + hl];
            float gi  = Ss[(3 * GH + hl) * 17 + col] + bias_s[3 * GH + hl];
            float gg  = Ss[(4 * GH + hl) * 17 + col] + bias_s[4 * GH + hl];
            float so = sigm(go), sfl = sigm(gfl), sfu = sigm(gfu), si = sigm(gi);
            float tg = tanh_fast(gg);
            float cp = Cs[(col + 1) * GH + hl];
            float cs = hr ? Cs[col * GH + hl] : 0.f;
            float cv = sfl * cp + sfu * cs + si * tg;
            float hv = so * tanh_fast(cv);
            size_t sidx = (size_t)n * HD_ + hd;
            gstore(cn + sidx, cv);
            gstore(hn + sidx, hv);
            int w = j - hr;
            if ((unsigned)w < (unsigned)W_)
                out[(((size_t)b * HD_ + hd) * H_ + hr) * W_ + w] = hv;
        }
        __syncthreads();
        if (tid == 0) bump(cntp + cgp * 32);    // step j finished
    }
}

// ---------------------------------------------------------------------------
extern "C" void kernel_launch(void* const* d_in, const int* in_sizes, int n_in,
                              void* d_out, int out_size, void* d_ws, size_t ws_size,
                              hipStream_t stream)
{
    const float* x    = (const float*)d_in[0];
    const float* w_is = (const float*)d_in[1];
    const float* b_is = (const float*)d_in[2];
    const float* w_ss = (const float*)d_in[3];
    const float* b_ss = (const float*)d_in[4];
    float* out = (float*)d_out;
    float* ws  = (float*)d_ws;

    const long long n_ws = (long long)(ws_size / 4);
    const int use_xt = (n_ws >= WS_XT) ? 1 : 0;

    hipLaunchKernelGGL(lstm_prep, dim3(2048), dim3(256), 0, stream,
                       x, w_is, w_ss, ws, use_xt, n_ws);

    hipLaunchKernelGGL(lstm_persist, dim3(NG * NCG), dim3(NT), 0, stream,
                       x, ws, b_is, b_ss, out, ws, use_xt);
}